// Round 3
// baseline (649.181 us; speedup 1.0000x reference)
//
#include <hip/hip_runtime.h>
#include <hip/hip_bf16.h>
#include <stdint.h>

// ---------- types ----------
typedef __attribute__((ext_vector_type(4))) float  f32x4;
typedef __attribute__((ext_vector_type(8))) short  bf16x8;
typedef __attribute__((ext_vector_type(8))) unsigned short u16x8;

#define MFMA16(d, x, y) d = __builtin_amdgcn_mfma_f32_16x16x32_bf16(x, y, d, 0, 0, 0)

// round f32 -> bf16 bits (RNE)
static __device__ inline unsigned short f2bf(float f) {
    union { float f; unsigned u; } a; a.f = f;
    unsigned u = a.u;
    unsigned lsb = (u >> 16) & 1u;
    u += 0x7fffu + lsb;
    return (unsigned short)(u >> 16);
}

// Emulate reference fp8_e4m3_round for positive x (x >= 1e-12).
static __device__ inline float fp8_e4m3_round(float x) {
    union { float f; unsigned u; } a; a.f = x;
    int e = (int)((a.u >> 23) & 255u) - 127;   // floor(log2(x)) exactly
    e = e < -6 ? -6 : (e > 8 ? 8 : e);
    union { unsigned u; float f; } stp, inv;
    stp.u = (unsigned)(e - 3 + 127) << 23;     // 2^(e-3)
    inv.u = (unsigned)(3 - e + 127) << 23;     // 2^(3-e)
    float r = rintf(x * inv.f) * stp.f;        // round-half-even == jnp.round
    return fminf(r, 448.0f);
}

// fp4 e2m1 level by strict midpoint comparison
static __device__ inline float fp4_level(float a) {
    return a > 2.5f ? (a > 3.5f ? (a > 5.0f ? 6.0f : 4.0f) : 3.0f)
                    : (a > 1.25f ? (a > 1.75f ? 2.0f : 1.5f)
                                 : (a > 0.75f ? 1.0f : (a > 0.25f ? 0.5f : 0.0f)));
}

// ---------- kernel 1: quantize+dequantize activations to bf16 ----------
__global__ void quant_x_kernel(const float* __restrict__ x, unsigned short* __restrict__ xd, int nblk) {
    int i = blockIdx.x * blockDim.x + threadIdx.x;
    if (i >= nblk) return;
    const float4* p = (const float4*)(x + (size_t)i * 16);
    float4 v0 = p[0], v1 = p[1], v2 = p[2], v3 = p[3];
    float vals[16] = { v0.x,v0.y,v0.z,v0.w, v1.x,v1.y,v1.z,v1.w,
                       v2.x,v2.y,v2.z,v2.w, v3.x,v3.y,v3.z,v3.w };
    float amax = 0.0f;
#pragma unroll
    for (int j = 0; j < 16; ++j) amax = fmaxf(amax, fabsf(vals[j]));
    float s0 = fmaxf(amax / 6.0f, 1e-12f);
    float s  = fmaxf(fp8_e4m3_round(s0), 1.0f / 512.0f);  // FP8_MIN = 2^-9
    u16x8 o0, o1;
#pragma unroll
    for (int j = 0; j < 16; ++j) {
        float v = vals[j] / s;
        float lev = fp4_level(fabsf(v));
        float q = copysignf(lev, v);
        unsigned short b = f2bf(q * s);
        if (j < 8) o0[j] = b; else o1[j - 8] = b;
    }
    u16x8* dst = (u16x8*)(xd + (size_t)i * 16);
    dst[0] = o0; dst[1] = o1;
}

// ---------- kernel 2: dequantize weights to bf16 ----------
__global__ void deq_w_kernel(const float* __restrict__ wq, const float* __restrict__ wsc,
                             unsigned short* __restrict__ wd, int nblk) {
    int i = blockIdx.x * blockDim.x + threadIdx.x;
    if (i >= nblk) return;
    float s = wsc[i];
    const float4* p = (const float4*)(wq + (size_t)i * 16);
    float4 v0 = p[0], v1 = p[1], v2 = p[2], v3 = p[3];
    float vals[16] = { v0.x,v0.y,v0.z,v0.w, v1.x,v1.y,v1.z,v1.w,
                       v2.x,v2.y,v2.z,v2.w, v3.x,v3.y,v3.z,v3.w };
    u16x8 o0, o1;
#pragma unroll
    for (int j = 0; j < 16; ++j) {
        unsigned short b = f2bf(vals[j] * s);
        if (j < 8) o0[j] = b; else o1[j - 8] = b;
    }
    u16x8* dst = (u16x8*)(wd + (size_t)i * 16);
    dst[0] = o0; dst[1] = o1;
}

// ---------- kernel 3: 256x256x64 8-phase pipelined bf16 GEMM ----------
// C[M][N] = A[M][K] * B[N][K]^T + bias.  8 waves (2Mx4N), per-wave 128x64.
// LDS (128KB): A: [buf][kslice][rowgroup 0..15] 1024B subtiles at 0 / 32768
//              B: same at 65536.
// FRAGMENT-MAJOR subtile layout: physical byte = kgroup*256 + row*16.
// => every ds_read is base + lane*16 (+subtile*1024): consecutive lanes hit
// consecutive banks -> ZERO bank conflicts by construction.
// Inverse permutation lives on the global_load_lds SOURCE address (per-lane
// scatter is legal; LDS dest stays wave-linear): staging lane l fetches
// global (row = l&15, k-elems = (l>>4)*8).
// Schedule: per tile 4 phases; stage 1 half-tile (2 loads) per phase; vmcnt(6)
// at phases 1,3 only (every half staged >=6 phases before its read).
static __device__ __forceinline__ void stage_half(const unsigned short* g0, const unsigned short* g1,
                                                  size_t koff, char* d0) {
    __builtin_amdgcn_global_load_lds((const __attribute__((address_space(1))) void*)(g0 + koff),
                                     (__attribute__((address_space(3))) void*)d0, 16, 0, 0);
    __builtin_amdgcn_global_load_lds((const __attribute__((address_space(1))) void*)(g1 + koff),
                                     (__attribute__((address_space(3))) void*)(d0 + 1024), 16, 0, 0);
}

__global__ __launch_bounds__(512, 2)
void gemm_kernel(const unsigned short* __restrict__ A, const unsigned short* __restrict__ Bw,
                 const float* __restrict__ bias, float* __restrict__ C,
                 int M, int N, int K) {
    extern __shared__ char lds[];
    const int tid  = threadIdx.x;
    const int lane = tid & 63;
    const int wid  = tid >> 6;
    const int wr   = wid >> 2;       // 0..1
    const int wc   = wid & 3;        // 0..3

    const int NXB = N >> 8, NYB = M >> 8;
    int bid = blockIdx.x;
    int bx, by;
    if (NXB == 64 && NYB == 16) {    // XCD-aware swizzle (8 XCDs, 1024 wgs)
        int xcd = bid & 7, c = bid >> 3;
        bx = xcd * 8 + (c & 7);
        by = c >> 3;
    } else { bx = bid % NXB; by = bid / NXB; }

    const int NT = K >> 6;           // K-tiles of 64

    // fragment-major: reads are wave-linear; global source carries the permutation
    const int lane_off = lane * 16;
    const int r_l = lane & 15;        // global row within 16-row subtile
    const int c_l = (lane >> 4) * 8;  // global k-element offset

    const unsigned short* gA0 = A  + (size_t)(by * 256 + wid * 32 + r_l) * K + c_l;
    const unsigned short* gA1 = gA0 + (size_t)16 * K;
    const unsigned short* gB0 = Bw + (size_t)(bx * 256 + wid * 32 + r_l) * K + c_l;
    const unsigned short* gB1 = gB0 + (size_t)16 * K;
    char* ldsA_w = lds + wid * 2048 + lane * 16;           // + b*32768 + s*16384
    char* ldsB_w = lds + 65536 + wid * 2048 + lane * 16;

    f32x4 acc[8][4];
#pragma unroll
    for (int m = 0; m < 8; ++m)
#pragma unroll
        for (int n = 0; n < 4; ++n)
#pragma unroll
            for (int j = 0; j < 4; ++j) acc[m][n][j] = 0.0f;

    // ---- prologue: stage halves H0..H6 (tile0 all, tile1 A-k0,B-k0,A-k1) ----
    stage_half(gA0, gA1, 0,   ldsA_w);
    stage_half(gB0, gB1, 0,   ldsB_w);
    stage_half(gA0, gA1, 32,  ldsA_w + 16384);
    stage_half(gB0, gB1, 32,  ldsB_w + 16384);
    stage_half(gA0, gA1, 64,  ldsA_w + 32768);
    stage_half(gB0, gB1, 64,  ldsB_w + 32768);
    stage_half(gA0, gA1, 96,  ldsA_w + 32768 + 16384);
    asm volatile("s_waitcnt vmcnt(6)" ::: "memory");       // tile0 halves landed
    __builtin_amdgcn_s_barrier();

    bf16x8 a[8], bq[4];

    // ---- main loop: tiles 0 .. NT-3 ----
    for (int t = 0; t <= NT - 3; ++t) {
        const int b = t & 1;
        const char* pA = lds + b * 32768 + wr * 8192 + lane_off;
        const char* pB = lds + 65536 + b * 32768 + wc * 4096 + lane_off;
        char* dA2 = ldsA_w + b * 32768;                    // (t+2)&1 == b
        char* dB1 = ldsB_w + ((t + 1) & 1) * 32768;
        char* dB2 = ldsB_w + b * 32768;
        const size_t k1off = (size_t)(t + 1) * 64;
        const size_t k2off = (size_t)(t + 2) * 64;

        // ---------- phase 1: A k0 (8) + B k0 nf0,1 ; stage B-k1[t+1] ----------
        asm volatile("s_waitcnt vmcnt(6)" ::: "memory");
#pragma unroll
        for (int mf = 0; mf < 8; ++mf) a[mf] = *(const bf16x8*)(pA + mf * 1024);
        bq[0] = *(const bf16x8*)(pB);
        bq[1] = *(const bf16x8*)(pB + 1024);
        stage_half(gB0, gB1, k1off + 32, dB1 + 16384);
        __builtin_amdgcn_s_barrier();
        asm volatile("s_waitcnt lgkmcnt(0)" ::: "memory");
        __builtin_amdgcn_s_setprio(1);
#pragma unroll
        for (int mf = 0; mf < 8; ++mf) { MFMA16(acc[mf][0], a[mf], bq[0]); MFMA16(acc[mf][1], a[mf], bq[1]); }
        __builtin_amdgcn_s_setprio(0);
        __builtin_amdgcn_s_barrier();

        // ---------- phase 2: B k0 nf2,3 ; stage A-k0[t+2] ----------
        bq[2] = *(const bf16x8*)(pB + 2048);
        bq[3] = *(const bf16x8*)(pB + 3072);
        stage_half(gA0, gA1, k2off, dA2);
        __builtin_amdgcn_s_barrier();
        asm volatile("s_waitcnt lgkmcnt(0)" ::: "memory");
        __builtin_amdgcn_s_setprio(1);
#pragma unroll
        for (int mf = 0; mf < 8; ++mf) { MFMA16(acc[mf][2], a[mf], bq[2]); MFMA16(acc[mf][3], a[mf], bq[3]); }
        __builtin_amdgcn_s_setprio(0);
        __builtin_amdgcn_s_barrier();

        // ---------- phase 3: A k1 (8) + B k1 nf0,1 ; stage B-k0[t+2] ----------
        asm volatile("s_waitcnt vmcnt(6)" ::: "memory");
#pragma unroll
        for (int mf = 0; mf < 8; ++mf) a[mf] = *(const bf16x8*)(pA + 16384 + mf * 1024);
        bq[0] = *(const bf16x8*)(pB + 16384);
        bq[1] = *(const bf16x8*)(pB + 16384 + 1024);
        stage_half(gB0, gB1, k2off, dB2);
        __builtin_amdgcn_s_barrier();
        asm volatile("s_waitcnt lgkmcnt(0)" ::: "memory");
        __builtin_amdgcn_s_setprio(1);
#pragma unroll
        for (int mf = 0; mf < 8; ++mf) { MFMA16(acc[mf][0], a[mf], bq[0]); MFMA16(acc[mf][1], a[mf], bq[1]); }
        __builtin_amdgcn_s_setprio(0);
        __builtin_amdgcn_s_barrier();

        // ---------- phase 4: B k1 nf2,3 ; stage A-k1[t+2] ----------
        bq[2] = *(const bf16x8*)(pB + 16384 + 2048);
        bq[3] = *(const bf16x8*)(pB + 16384 + 3072);
        stage_half(gA0, gA1, k2off + 32, dA2 + 16384);
        __builtin_amdgcn_s_barrier();
        asm volatile("s_waitcnt lgkmcnt(0)" ::: "memory");
        __builtin_amdgcn_s_setprio(1);
#pragma unroll
        for (int mf = 0; mf < 8; ++mf) { MFMA16(acc[mf][2], a[mf], bq[2]); MFMA16(acc[mf][3], a[mf], bq[3]); }
        __builtin_amdgcn_s_setprio(0);
        __builtin_amdgcn_s_barrier();
    }

    // ---- epilogue: stage last missing half, drain, compute tiles NT-2, NT-1 ----
    {
        char* dBl = ldsB_w + ((NT - 1) & 1) * 32768;
        stage_half(gB0, gB1, (size_t)(NT - 1) * 64 + 32, dBl + 16384);
    }
    asm volatile("s_waitcnt vmcnt(0)" ::: "memory");
    __builtin_amdgcn_s_barrier();

#pragma unroll 1
    for (int tt = NT - 2; tt < NT; ++tt) {
        const int b = tt & 1;
        const char* pA = lds + b * 32768 + wr * 8192 + lane_off;
        const char* pB = lds + 65536 + b * 32768 + wc * 4096 + lane_off;
#pragma unroll
        for (int s = 0; s < 2; ++s) {
            bf16x8 a2[8], b2[4];
#pragma unroll
            for (int mf = 0; mf < 8; ++mf) a2[mf] = *(const bf16x8*)(pA + s * 16384 + mf * 1024);
#pragma unroll
            for (int nf = 0; nf < 4; ++nf) b2[nf] = *(const bf16x8*)(pB + s * 16384 + nf * 1024);
#pragma unroll
            for (int mf = 0; mf < 8; ++mf)
#pragma unroll
                for (int nf = 0; nf < 4; ++nf) MFMA16(acc[mf][nf], a2[mf], b2[nf]);
        }
    }

    // ---- C write: col = lane&15, row = (lane>>4)*4 + j ----
    const int row0 = by * 256 + wr * 128;
    const int col0 = bx * 256 + wc * 64;
#pragma unroll
    for (int nf = 0; nf < 4; ++nf) {
        int col = col0 + nf * 16 + (lane & 15);
        float bv = bias[col];
#pragma unroll
        for (int mf = 0; mf < 8; ++mf) {
#pragma unroll
            for (int j = 0; j < 4; ++j) {
                int row = row0 + mf * 16 + ((lane >> 4) << 2) + j;
                C[(size_t)row * N + col] = acc[mf][nf][j] + bv;
            }
        }
    }
}

// ---------- host ----------
extern "C" void kernel_launch(void* const* d_in, const int* in_sizes, int n_in,
                              void* d_out, int out_size, void* d_ws, size_t ws_size,
                              hipStream_t stream) {
    const float* x    = (const float*)d_in[0];
    const float* wq   = (const float*)d_in[1];
    const float* wsc  = (const float*)d_in[2];
    const float* bias = (const float*)d_in[3];
    float* out = (float*)d_out;

    const long N = in_sizes[3];                 // 16384
    const long K = (long)in_sizes[1] / N;       // 4096
    const long M = (long)in_sizes[0] / K;       // 4096

    size_t need = ((size_t)(M * K) + (size_t)(N * K)) * sizeof(unsigned short);
    if (ws_size < need) return;

    unsigned short* xd = (unsigned short*)d_ws;          // [M][K] bf16
    unsigned short* wd = xd + (size_t)M * K;             // [N][K] bf16

    {
        int nblk = (int)(M * K / 16);
        quant_x_kernel<<<(nblk + 255) / 256, 256, 0, stream>>>(x, xd, nblk);
    }
    {
        int nblk = (int)(N * K / 16);
        deq_w_kernel<<<(nblk + 255) / 256, 256, 0, stream>>>(wq, wsc, wd, nblk);
    }
    {
        hipFuncSetAttribute((const void*)gemm_kernel,
                            hipFuncAttributeMaxDynamicSharedMemorySize, 131072);
        int nwg = (int)((M / 256) * (N / 256));
        gemm_kernel<<<dim3(nwg), dim3(512), 131072, stream>>>(xd, wd, bias, out,
                                                              (int)M, (int)N, (int)K);
    }
}

// Round 4
// 539.897 us; speedup vs baseline: 1.2024x; 1.2024x over previous
//
#include <hip/hip_runtime.h>
#include <hip/hip_bf16.h>
#include <stdint.h>

// ---------- types ----------
typedef __attribute__((ext_vector_type(4))) float  f32x4;
typedef __attribute__((ext_vector_type(8))) short  bf16x8;
typedef __attribute__((ext_vector_type(8))) unsigned short u16x8;

#define MFMA16(d, x, y) d = __builtin_amdgcn_mfma_f32_16x16x32_bf16(x, y, d, 0, 0, 0)

// round f32 -> bf16 bits (RNE)
static __device__ inline unsigned short f2bf(float f) {
    union { float f; unsigned u; } a; a.f = f;
    unsigned u = a.u;
    unsigned lsb = (u >> 16) & 1u;
    u += 0x7fffu + lsb;
    return (unsigned short)(u >> 16);
}

// Emulate reference fp8_e4m3_round for positive x (x >= 1e-12).
static __device__ inline float fp8_e4m3_round(float x) {
    union { float f; unsigned u; } a; a.f = x;
    int e = (int)((a.u >> 23) & 255u) - 127;   // floor(log2(x)) exactly
    e = e < -6 ? -6 : (e > 8 ? 8 : e);
    union { unsigned u; float f; } stp, inv;
    stp.u = (unsigned)(e - 3 + 127) << 23;     // 2^(e-3)
    inv.u = (unsigned)(3 - e + 127) << 23;     // 2^(3-e)
    float r = rintf(x * inv.f) * stp.f;        // round-half-even == jnp.round
    return fminf(r, 448.0f);
}

// fp4 e2m1 level by strict midpoint comparison
static __device__ inline float fp4_level(float a) {
    return a > 2.5f ? (a > 3.5f ? (a > 5.0f ? 6.0f : 4.0f) : 3.0f)
                    : (a > 1.25f ? (a > 1.75f ? 2.0f : 1.5f)
                                 : (a > 0.75f ? 1.0f : (a > 0.25f ? 0.5f : 0.0f)));
}

// ---------- kernel 1: quantize+dequantize activations to bf16 ----------
__global__ void quant_x_kernel(const float* __restrict__ x, unsigned short* __restrict__ xd, int nblk) {
    int i = blockIdx.x * blockDim.x + threadIdx.x;
    if (i >= nblk) return;
    const float4* p = (const float4*)(x + (size_t)i * 16);
    float4 v0 = p[0], v1 = p[1], v2 = p[2], v3 = p[3];
    float vals[16] = { v0.x,v0.y,v0.z,v0.w, v1.x,v1.y,v1.z,v1.w,
                       v2.x,v2.y,v2.z,v2.w, v3.x,v3.y,v3.z,v3.w };
    float amax = 0.0f;
#pragma unroll
    for (int j = 0; j < 16; ++j) amax = fmaxf(amax, fabsf(vals[j]));
    float s0 = fmaxf(amax / 6.0f, 1e-12f);
    float s  = fmaxf(fp8_e4m3_round(s0), 1.0f / 512.0f);  // FP8_MIN = 2^-9
    u16x8 o0, o1;
#pragma unroll
    for (int j = 0; j < 16; ++j) {
        float v = vals[j] / s;
        float lev = fp4_level(fabsf(v));
        float q = copysignf(lev, v);
        unsigned short b = f2bf(q * s);
        if (j < 8) o0[j] = b; else o1[j - 8] = b;
    }
    u16x8* dst = (u16x8*)(xd + (size_t)i * 16);
    dst[0] = o0; dst[1] = o1;
}

// ---------- kernel 2: dequantize weights to bf16 ----------
__global__ void deq_w_kernel(const float* __restrict__ wq, const float* __restrict__ wsc,
                             unsigned short* __restrict__ wd, int nblk) {
    int i = blockIdx.x * blockDim.x + threadIdx.x;
    if (i >= nblk) return;
    float s = wsc[i];
    const float4* p = (const float4*)(wq + (size_t)i * 16);
    float4 v0 = p[0], v1 = p[1], v2 = p[2], v3 = p[3];
    float vals[16] = { v0.x,v0.y,v0.z,v0.w, v1.x,v1.y,v1.z,v1.w,
                       v2.x,v2.y,v2.z,v2.w, v3.x,v3.y,v3.z,v3.w };
    u16x8 o0, o1;
#pragma unroll
    for (int j = 0; j < 16; ++j) {
        unsigned short b = f2bf(vals[j] * s);
        if (j < 8) o0[j] = b; else o1[j - 8] = b;
    }
    u16x8* dst = (u16x8*)(wd + (size_t)i * 16);
    dst[0] = o0; dst[1] = o1;
}

// ---------- kernel 3: 256x256x64 8-phase pipelined bf16 GEMM ----------
// C[M][N] = A[M][K] * B[N][K]^T + bias.  8 waves (2Mx4N), per-wave 128x64.
// LDS (128KB): A: [buf][kslice][rowgroup 0..15][16][32]bf16 subtiles at 0/32768
//              B: same at 65536.
// m201-EXACT st_16x32 swizzle (ONE bit): byte ^= ((byte>>9)&1)<<5 within each
// 1024B subtile.  Applied both-sides: swizzled ds_read addr + inverse-swizzled
// global_load_lds SOURCE (LDS dest stays wave-linear).  Source stays coalesced:
// 4 consecutive lanes cover 64 contiguous bytes of one row.
// Schedule: per tile 4 phases; stage 1 half-tile (2 loads) per phase; vmcnt(6)
// at phases 1,3 only (every half staged >=6 phases before its read).
static __device__ __forceinline__ void stage_half(const unsigned short* g0, const unsigned short* g1,
                                                  size_t koff, char* d0) {
    __builtin_amdgcn_global_load_lds((const __attribute__((address_space(1))) void*)(g0 + koff),
                                     (__attribute__((address_space(3))) void*)d0, 16, 0, 0);
    __builtin_amdgcn_global_load_lds((const __attribute__((address_space(1))) void*)(g1 + koff),
                                     (__attribute__((address_space(3))) void*)(d0 + 1024), 16, 0, 0);
}

__global__ __launch_bounds__(512, 2)
void gemm_kernel(const unsigned short* __restrict__ A, const unsigned short* __restrict__ Bw,
                 const float* __restrict__ bias, float* __restrict__ C,
                 int M, int N, int K) {
    extern __shared__ char lds[];
    const int tid  = threadIdx.x;
    const int lane = tid & 63;
    const int wid  = tid >> 6;
    const int wr   = wid >> 2;       // 0..1
    const int wc   = wid & 3;        // 0..3

    const int NXB = N >> 8, NYB = M >> 8;
    int bid = blockIdx.x;
    int bx, by;
    if (NXB == 64 && NYB == 16) {    // XCD-aware swizzle (8 XCDs, 1024 wgs)
        int xcd = bid & 7, c = bid >> 3;
        bx = xcd * 8 + (c & 7);
        by = c >> 3;
    } else { bx = bid % NXB; by = bid / NXB; }

    const int NT = K >> 6;           // K-tiles of 64

    // read-side swizzled lane offset within a 1024B subtile (st_16x32, 1 bit)
    int w0 = (lane & 15) * 64 + ((lane >> 4) << 4);
    const int lane_off = w0 ^ (((w0 >> 9) & 1) << 5);
    // write-side inverse permutation: lane -> (row, col) within subtile
    const int u   = (lane * 16) ^ (lane & 32);   // bit9 of lane*16 == lane&32
    const int r_l = u >> 6;
    const int c_l = (u & 63) >> 1;

    const unsigned short* gA0 = A  + (size_t)(by * 256 + wid * 32 + r_l) * K + c_l;
    const unsigned short* gA1 = gA0 + (size_t)16 * K;
    const unsigned short* gB0 = Bw + (size_t)(bx * 256 + wid * 32 + r_l) * K + c_l;
    const unsigned short* gB1 = gB0 + (size_t)16 * K;
    char* ldsA_w = lds + wid * 2048 + lane * 16;           // + b*32768 + s*16384
    char* ldsB_w = lds + 65536 + wid * 2048 + lane * 16;

    f32x4 acc[8][4];
#pragma unroll
    for (int m = 0; m < 8; ++m)
#pragma unroll
        for (int n = 0; n < 4; ++n)
#pragma unroll
            for (int j = 0; j < 4; ++j) acc[m][n][j] = 0.0f;

    // ---- prologue: stage halves H0..H6 (tile0 all, tile1 A-k0,B-k0,A-k1) ----
    stage_half(gA0, gA1, 0,   ldsA_w);
    stage_half(gB0, gB1, 0,   ldsB_w);
    stage_half(gA0, gA1, 32,  ldsA_w + 16384);
    stage_half(gB0, gB1, 32,  ldsB_w + 16384);
    stage_half(gA0, gA1, 64,  ldsA_w + 32768);
    stage_half(gB0, gB1, 64,  ldsB_w + 32768);
    stage_half(gA0, gA1, 96,  ldsA_w + 32768 + 16384);
    asm volatile("s_waitcnt vmcnt(6)" ::: "memory");       // tile0 halves landed
    __builtin_amdgcn_s_barrier();

    bf16x8 a[8], bq[4];

    // ---- main loop: tiles 0 .. NT-3 ----
    for (int t = 0; t <= NT - 3; ++t) {
        const int b = t & 1;
        const char* pA = lds + b * 32768 + wr * 8192 + lane_off;
        const char* pB = lds + 65536 + b * 32768 + wc * 4096 + lane_off;
        char* dA2 = ldsA_w + b * 32768;                    // (t+2)&1 == b
        char* dB1 = ldsB_w + ((t + 1) & 1) * 32768;
        char* dB2 = ldsB_w + b * 32768;
        const size_t k1off = (size_t)(t + 1) * 64;
        const size_t k2off = (size_t)(t + 2) * 64;

        // ---------- phase 1: A k0 (8) + B k0 nf0,1 ; stage B-k1[t+1] ----------
        asm volatile("s_waitcnt vmcnt(6)" ::: "memory");
#pragma unroll
        for (int mf = 0; mf < 8; ++mf) a[mf] = *(const bf16x8*)(pA + mf * 1024);
        bq[0] = *(const bf16x8*)(pB);
        bq[1] = *(const bf16x8*)(pB + 1024);
        stage_half(gB0, gB1, k1off + 32, dB1 + 16384);
        __builtin_amdgcn_s_barrier();
        asm volatile("s_waitcnt lgkmcnt(0)" ::: "memory");
        __builtin_amdgcn_s_setprio(1);
#pragma unroll
        for (int mf = 0; mf < 8; ++mf) { MFMA16(acc[mf][0], a[mf], bq[0]); MFMA16(acc[mf][1], a[mf], bq[1]); }
        __builtin_amdgcn_s_setprio(0);
        __builtin_amdgcn_s_barrier();

        // ---------- phase 2: B k0 nf2,3 ; stage A-k0[t+2] ----------
        bq[2] = *(const bf16x8*)(pB + 2048);
        bq[3] = *(const bf16x8*)(pB + 3072);
        stage_half(gA0, gA1, k2off, dA2);
        __builtin_amdgcn_s_barrier();
        asm volatile("s_waitcnt lgkmcnt(0)" ::: "memory");
        __builtin_amdgcn_s_setprio(1);
#pragma unroll
        for (int mf = 0; mf < 8; ++mf) { MFMA16(acc[mf][2], a[mf], bq[2]); MFMA16(acc[mf][3], a[mf], bq[3]); }
        __builtin_amdgcn_s_setprio(0);
        __builtin_amdgcn_s_barrier();

        // ---------- phase 3: A k1 (8) + B k1 nf0,1 ; stage B-k0[t+2] ----------
        asm volatile("s_waitcnt vmcnt(6)" ::: "memory");
#pragma unroll
        for (int mf = 0; mf < 8; ++mf) a[mf] = *(const bf16x8*)(pA + 16384 + mf * 1024);
        bq[0] = *(const bf16x8*)(pB + 16384);
        bq[1] = *(const bf16x8*)(pB + 16384 + 1024);
        stage_half(gB0, gB1, k2off, dB2);
        __builtin_amdgcn_s_barrier();
        asm volatile("s_waitcnt lgkmcnt(0)" ::: "memory");
        __builtin_amdgcn_s_setprio(1);
#pragma unroll
        for (int mf = 0; mf < 8; ++mf) { MFMA16(acc[mf][0], a[mf], bq[0]); MFMA16(acc[mf][1], a[mf], bq[1]); }
        __builtin_amdgcn_s_setprio(0);
        __builtin_amdgcn_s_barrier();

        // ---------- phase 4: B k1 nf2,3 ; stage A-k1[t+2] ----------
        bq[2] = *(const bf16x8*)(pB + 16384 + 2048);
        bq[3] = *(const bf16x8*)(pB + 16384 + 3072);
        stage_half(gA0, gA1, k2off + 32, dA2 + 16384);
        __builtin_amdgcn_s_barrier();
        asm volatile("s_waitcnt lgkmcnt(0)" ::: "memory");
        __builtin_amdgcn_s_setprio(1);
#pragma unroll
        for (int mf = 0; mf < 8; ++mf) { MFMA16(acc[mf][2], a[mf], bq[2]); MFMA16(acc[mf][3], a[mf], bq[3]); }
        __builtin_amdgcn_s_setprio(0);
        __builtin_amdgcn_s_barrier();
    }

    // ---- epilogue: stage last missing half, drain, compute tiles NT-2, NT-1 ----
    {
        char* dBl = ldsB_w + ((NT - 1) & 1) * 32768;
        stage_half(gB0, gB1, (size_t)(NT - 1) * 64 + 32, dBl + 16384);
    }
    asm volatile("s_waitcnt vmcnt(0)" ::: "memory");
    __builtin_amdgcn_s_barrier();

#pragma unroll 1
    for (int tt = NT - 2; tt < NT; ++tt) {
        const int b = tt & 1;
        const char* pA = lds + b * 32768 + wr * 8192 + lane_off;
        const char* pB = lds + 65536 + b * 32768 + wc * 4096 + lane_off;
#pragma unroll
        for (int s = 0; s < 2; ++s) {
            bf16x8 a2[8], b2[4];
#pragma unroll
            for (int mf = 0; mf < 8; ++mf) a2[mf] = *(const bf16x8*)(pA + s * 16384 + mf * 1024);
#pragma unroll
            for (int nf = 0; nf < 4; ++nf) b2[nf] = *(const bf16x8*)(pB + s * 16384 + nf * 1024);
#pragma unroll
            for (int mf = 0; mf < 8; ++mf)
#pragma unroll
                for (int nf = 0; nf < 4; ++nf) MFMA16(acc[mf][nf], a2[mf], b2[nf]);
        }
    }

    // ---- C write: col = lane&15, row = (lane>>4)*4 + j ----
    const int row0 = by * 256 + wr * 128;
    const int col0 = bx * 256 + wc * 64;
#pragma unroll
    for (int nf = 0; nf < 4; ++nf) {
        int col = col0 + nf * 16 + (lane & 15);
        float bv = bias[col];
#pragma unroll
        for (int mf = 0; mf < 8; ++mf) {
#pragma unroll
            for (int j = 0; j < 4; ++j) {
                int row = row0 + mf * 16 + ((lane >> 4) << 2) + j;
                C[(size_t)row * N + col] = acc[mf][nf][j] + bv;
            }
        }
    }
}

// ---------- host ----------
extern "C" void kernel_launch(void* const* d_in, const int* in_sizes, int n_in,
                              void* d_out, int out_size, void* d_ws, size_t ws_size,
                              hipStream_t stream) {
    const float* x    = (const float*)d_in[0];
    const float* wq   = (const float*)d_in[1];
    const float* wsc  = (const float*)d_in[2];
    const float* bias = (const float*)d_in[3];
    float* out = (float*)d_out;

    const long N = in_sizes[3];                 // 16384
    const long K = (long)in_sizes[1] / N;       // 4096
    const long M = (long)in_sizes[0] / K;       // 4096

    size_t need = ((size_t)(M * K) + (size_t)(N * K)) * sizeof(unsigned short);
    if (ws_size < need) return;

    unsigned short* xd = (unsigned short*)d_ws;          // [M][K] bf16
    unsigned short* wd = xd + (size_t)M * K;             // [N][K] bf16

    {
        int nblk = (int)(M * K / 16);
        quant_x_kernel<<<(nblk + 255) / 256, 256, 0, stream>>>(x, xd, nblk);
    }
    {
        int nblk = (int)(N * K / 16);
        deq_w_kernel<<<(nblk + 255) / 256, 256, 0, stream>>>(wq, wsc, wd, nblk);
    }
    {
        hipFuncSetAttribute((const void*)gemm_kernel,
                            hipFuncAttributeMaxDynamicSharedMemorySize, 131072);
        int nwg = (int)((M / 256) * (N / 256));
        gemm_kernel<<<dim3(nwg), dim3(512), 131072, stream>>>(xd, wd, bias, out,
                                                              (int)M, (int)N, (int)K);
    }
}